// Round 2
// baseline (1241.679 us; speedup 1.0000x reference)
//
#include <hip/hip_runtime.h>
#include <stdint.h>

// ---------------------------------------------------------------------------
// QuantizedLinear: out[M,N] = x[M,K] @ dequant(Wpacked)[N,K]^T
//   M = 8192, K = 4096, N = 4096
// R7: prepass unchanged. GEMM: 256x256 tile, BK=64, 8 waves (2Mx4N),
// 32x32x16 bf16 MFMA, read-ahead-by-one-phase register pipeline:
//   phase p = [barrier; sched_barrier; ds_reads for FUTURE phase; stage one
//              half-tile; setprio(1); 8 MFMA on regs read LAST phase;
//              setprio(0); sched_barrier; vmcnt(6)]
// One barrier per phase (4/tile, was 8). LDS service overlaps MFMA.
// Counted vmcnt(6) = 3 half-tiles in flight; a half staged at phase p is
// drained by the vmcnt at end of p+3 and read at p+4 (collectivized by the
// barrier). Race ledger:
//   read-after-stage: 4-phase stage->read lead + vmcnt(6)+barrier  [safe]
//   stage-after-read: every stage hits a region whose reads drained >=2
//     barriers earlier (regs hold the data)                        [safe]
//   reg WAR: per-phase read targets never overlap that phase's MFMA
//     operands; A roles alternate per tile via unroll-2 (static)   [safe]
// Reg budget: acc 128 (AGPR) + A 64 + B 32 + addr ~24 = ~248 <= 256.
// ---------------------------------------------------------------------------

typedef short short8   __attribute__((ext_vector_type(8)));    // 8 bf16
typedef float floatx16 __attribute__((ext_vector_type(16)));   // 32x32 acc

#define BK 64

// round-to-nearest-even fp32 -> bf16 (returned in low 16 bits)
__device__ __forceinline__ uint32_t f2bf(float f) {
  union { float f; uint32_t u; } v; v.f = f;
  return (v.u + 0x7FFFu + ((v.u >> 16) & 1u)) >> 16;
}

// async global->LDS, 16B per lane; LDS dest is wave-uniform base + lane*16
__device__ __forceinline__ void async_copy16(const void* g, void* l) {
  __builtin_amdgcn_global_load_lds(
      (const __attribute__((address_space(1))) uint32_t*)g,
      (__attribute__((address_space(3))) uint32_t*)l, 16, 0, 0);
}

// ----------------- fused prepass: x -> bf16  and  W -> bf16 ----------------
__global__ void prep_kernel(const float4* __restrict__ x, uint4* __restrict__ xb,
                            int xblocks,
                            const int* __restrict__ wp, const float* __restrict__ cent,
                            const float* __restrict__ scales,
                            unsigned short* __restrict__ wb, int K) {
  if ((int)blockIdx.x < xblocks) {
    int t = blockIdx.x * blockDim.x + threadIdx.x;
    float4 v0 = x[4 * t + 0];
    float4 v1 = x[4 * t + 1];
    float4 v2 = x[4 * t + 2];
    float4 v3 = x[4 * t + 3];
    uint4 o0, o1;
    o0.x = f2bf(v0.x) | (f2bf(v0.y) << 16);
    o0.y = f2bf(v0.z) | (f2bf(v0.w) << 16);
    o0.z = f2bf(v1.x) | (f2bf(v1.y) << 16);
    o0.w = f2bf(v1.z) | (f2bf(v1.w) << 16);
    o1.x = f2bf(v2.x) | (f2bf(v2.y) << 16);
    o1.y = f2bf(v2.z) | (f2bf(v2.w) << 16);
    o1.z = f2bf(v3.x) | (f2bf(v3.y) << 16);
    o1.w = f2bf(v3.z) | (f2bf(v3.w) << 16);
    xb[2 * t]     = o0;
    xb[2 * t + 1] = o1;
  } else {
    __shared__ float lut[16];
    if (threadIdx.x < 16) lut[threadIdx.x] = cent[threadIdx.x];
    __syncthreads();
    int u = (blockIdx.x - xblocks) * blockDim.x + threadIdx.x;
    const int tpr = K >> 4;            // threads per row = 256 (pow2)
    int o = u / tpr;
    int j = u & (tpr - 1);
    const int* base = wp + (size_t)o * (K >> 1) + j * 8;
    const int4 p0 = *(const int4*)(base);
    const int4 p1 = *(const int4*)(base + 4);
    int kbase = j * 16;                // 16 weights, single 64-block
    float s = scales[(size_t)o * (K >> 6) + (kbase >> 6)];
    int pb[8] = {p0.x, p0.y, p0.z, p0.w, p1.x, p1.y, p1.z, p1.w};
    uint32_t w32[8];
#pragma unroll
    for (int i = 0; i < 8; ++i) {
      unsigned b = (unsigned)pb[i] & 0xFFu;
      uint32_t hi = f2bf(lut[b >> 4] * s);   // first element of the byte
      uint32_t lo = f2bf(lut[b & 15] * s);   // second element
      w32[i] = hi | (lo << 16);
    }
    uint4* dst = (uint4*)(wb + (size_t)o * K + kbase);
    dst[0] = make_uint4(w32[0], w32[1], w32[2], w32[3]);
    dst[1] = make_uint4(w32[4], w32[5], w32[6], w32[7]);
  }
}

// ------------------------------ main GEMM ----------------------------------
// A[M,K] bf16, B[N,K] bf16 (B^T layout), C[M,N] fp32.
// LDS per buffer: A[256][64] then B[256][64] (shorts). 16B-slot (row,p)
// holds global k-block p ^ (row&7) (involution; write side pre-swizzles the
// global source, read side XORs the same term).
// Phase schedule per tile T (buf = T&1), MFMA order q00,q10,q11,q01:
//   ph1: MFMA(X=A0(T), bA=B0(T)); read A1(T)->Y;      stage A1(T+1)
//   ph2: MFMA(Y=A1(T), bA);       read B1(T)->bB;     stage B1(T+1)
//   ph3: MFMA(Y, bB=B1(T));       read B0(T+1)->bA;   stage B0(T+2)
//   ph4: MFMA(X, bB);             read A0(T+1)->Y;    stage A0(T+2)
// A-holders X,Y swap each tile (unroll-2, static reg indices).
__global__ __launch_bounds__(512, 2) void gemm_bt8(const unsigned short* __restrict__ A,
                                                   const unsigned short* __restrict__ B,
                                                   float* __restrict__ C,
                                                   int M, int N, int K) {
  __shared__ unsigned short lds[65536];  // 128 KiB
  const int tid  = threadIdx.x;
  const int lane = tid & 63;
  const int w    = tid >> 6;     // wave 0..7
  const int wm   = w >> 2;       // 2 waves in M (128 rows each)
  const int wn   = w & 3;        // 4 waves in N (64 cols each)

  // bijective XCD-aware block swizzle (nwg = 512, %8 == 0)
  const int nbx = N >> 8;
  const int nwg = gridDim.x;
  const int wg  = blockIdx.x;
  const int swz = ((nwg & 7) == 0) ? ((wg & 7) * (nwg >> 3) + (wg >> 3)) : wg;
  const int bm  = (swz / nbx) << 8;
  const int bn  = (swz % nbx) << 8;

  // ---- staging: pre-swizzled global source, linear LDS dest --------------
  const int srow = lane >> 3;                 // row within an 8-row chunk
  const int sblk = (lane & 7) ^ srow;         // pre-swizzled global 16B-block
  const size_t goff = (size_t)srow * K + sblk * 8;   // shorts
  const unsigned short* Ag = A + (size_t)bm * K + goff;
  const unsigned short* Bg = B + (size_t)bn * K + goff;

  const int nt = K / BK;   // 64

  // A half qm: rows {qm*64+[0,64)} u {128+qm*64+[0,64)}; 2 issues/wave.
  auto stageA = [&](int buf, int kt, int qm) {
#pragma unroll
    for (int i = 0; i < 2; ++i) {
      const int r0 = i * 128 + qm * 64 + w * 8;          // wave-uniform
      async_copy16(Ag + (size_t)r0 * K + kt,
                   (char*)lds + buf * 65536 + r0 * 128);
    }
  };
  // B half qn: rows {qn*32 + j*64 + [0,32) : j=0..3}
  auto stageB = [&](int buf, int kt, int qn) {
#pragma unroll
    for (int i = 0; i < 2; ++i) {
      const int j  = i * 2 + (w >> 2);
      const int r0 = qn * 32 + j * 64 + (w & 3) * 8;     // wave-uniform
      async_copy16(Bg + (size_t)r0 * K + kt,
                   (char*)lds + buf * 65536 + 32768 + r0 * 128);
    }
  };

  // ---- fragment reads (32x32x16: lane holds row lane&31, k (lane>>5)*8+j)
  const int lr = lane & 31;
  const int hi = lane >> 5;
  const int e  = lr & 7;          // row&7 swizzle term (row = 32*m + lr)

  // A half qm -> d[mtl*4+s], mtl in {0,1} (global mt = 2qm+mtl), s = k-step
  auto readA = [&](short8* d, int buf, int qm) {
#pragma unroll
    for (int q = 0; q < 8; ++q) {
      const int mtl = q >> 2, s = q & 3;
      d[q] = *(const short8*)(lds + buf * 32768 +
                              ((wm * 128 + (qm * 2 + mtl) * 32 + lr) << 6) +
                              (((2 * s + hi) ^ e) << 3));
    }
  };
  // B half qn -> d[s]
  auto readB = [&](short8* d, int buf, int qn) {
#pragma unroll
    for (int s = 0; s < 4; ++s) {
      d[s] = *(const short8*)(lds + buf * 32768 + 16384 +
                              ((wn * 64 + qn * 32 + lr) << 6) +
                              (((2 * s + hi) ^ e) << 3));
    }
  };

  floatx16 acc[4][2] = {};        // [m-tile][n-tile], 128 regs
  short8 aP[8], aQ[8];            // A halves (roles swap per tile)
  short8 bA[4], bB[4];            // B0 / B1 (roles fixed)

  auto mf8 = [&](const short8* AR, int mb, const short8* BR, int nc) {
#pragma unroll
    for (int s = 0; s < 4; ++s) {
      acc[mb + 0][nc] = __builtin_amdgcn_mfma_f32_32x32x16_bf16(AR[s],     BR[s], acc[mb + 0][nc], 0, 0, 0);
      acc[mb + 1][nc] = __builtin_amdgcn_mfma_f32_32x32x16_bf16(AR[4 + s], BR[s], acc[mb + 1][nc], 0, 0, 0);
    }
  };

  // ---- prologue: stage 6 halves (oldest-first = drain order), pre-read ---
  stageB(0, 0, 0);        // B0(0)   oldest
  stageA(0, 0, 0);        // A0(0)
  stageA(0, 0, 1);        // A1(0)
  stageB(0, 0, 1);        // B1(0)
  stageB(1, BK, 0);       // B0(1)
  stageA(1, BK, 0);       // A0(1)
  asm volatile("s_waitcnt vmcnt(6)" ::: "memory");  // drains B0(0),A0(0),A1(0)
  __builtin_amdgcn_s_barrier();
  __builtin_amdgcn_sched_barrier(0);
  readA(aP, 0, 0);        // X of tile 0 = A0(0)
  readB(bA, 0, 0);        // B0(0)

#define PHASE(RD, ST, MM)                                       \
  __builtin_amdgcn_s_barrier();                                 \
  __builtin_amdgcn_sched_barrier(0);                            \
  RD;                                                           \
  ST;                                                           \
  __builtin_amdgcn_s_setprio(1);                                \
  MM;                                                           \
  __builtin_amdgcn_s_setprio(0);                                \
  __builtin_amdgcn_sched_barrier(0);                            \
  asm volatile("s_waitcnt vmcnt(6)" ::: "memory");

#define TILE(T, X, Y, BUF)                                                     \
  PHASE(readA(Y, (BUF), 1),                                                    \
        if ((T) + 1 < nt) stageA((BUF) ^ 1, ((T) + 1) * BK, 1),                \
        mf8(X, 0, bA, 0))                                                      \
  PHASE(readB(bB, (BUF), 1),                                                   \
        if ((T) + 1 < nt) stageB((BUF) ^ 1, ((T) + 1) * BK, 1),                \
        mf8(Y, 2, bA, 0))                                                      \
  PHASE(if ((T) + 1 < nt) readB(bA, (BUF) ^ 1, 0),                             \
        if ((T) + 2 < nt) stageB((BUF), ((T) + 2) * BK, 0),                    \
        mf8(Y, 2, bB, 1))                                                      \
  PHASE(if ((T) + 1 < nt) readA(Y, (BUF) ^ 1, 0),                              \
        if ((T) + 2 < nt) stageA((BUF), ((T) + 2) * BK, 0),                    \
        mf8(X, 0, bB, 1))

  for (int T = 0; T < nt; T += 2) {
    TILE(T, aP, aQ, 0)
    TILE(T + 1, aQ, aP, 1)
  }
#undef TILE
#undef PHASE

  // ---- C store: 32x32 C/D layout (m74/m101):
  // col = lane&31, row = (reg&3) + 8*(reg>>2) + 4*(lane>>5)
#pragma unroll
  for (int mt = 0; mt < 4; ++mt)
#pragma unroll
    for (int ntl = 0; ntl < 2; ++ntl) {
      const floatx16 v = acc[mt][ntl];
      const int rb  = bm + wm * 128 + mt * 32 + 4 * hi;
      const int col = bn + wn * 64 + ntl * 32 + lr;
#pragma unroll
      for (int reg = 0; reg < 16; ++reg) {
        int row = rb + (reg & 3) + 8 * (reg >> 2);
        __builtin_nontemporal_store(v[reg], &C[(size_t)row * N + col]);
      }
    }
}

// ------------------------- fallback (ws too small) -------------------------
__global__ void naive_kernel(const float* __restrict__ x, const int* __restrict__ wp,
                             const float* __restrict__ cent, const float* __restrict__ scales,
                             float* __restrict__ out, int M, int N, int K) {
  __shared__ float lut[16];
  if (threadIdx.x < 16) lut[threadIdx.x] = cent[threadIdx.x];
  __syncthreads();
  int n = blockIdx.x * blockDim.x + threadIdx.x;
  int m = blockIdx.y;
  if (n >= N || m >= M) return;
  const float* xr = x + (size_t)m * K;
  const int* wr = wp + (size_t)n * (K / 2);
  float acc = 0.f;
  for (int kb = 0; kb < K / 64; ++kb) {
    float s = scales[(size_t)n * (K / 64) + kb];
    float a = 0.f;
    for (int j = 0; j < 32; ++j) {
      unsigned b = (unsigned)wr[kb * 32 + j] & 0xFFu;
      a += xr[kb * 64 + 2 * j] * lut[b >> 4] + xr[kb * 64 + 2 * j + 1] * lut[b & 15];
    }
    acc += a * s;
  }
  out[(size_t)m * N + n] = acc;
}

// ------------------------------- launcher ----------------------------------
extern "C" void kernel_launch(void* const* d_in, const int* in_sizes, int n_in,
                              void* d_out, int out_size, void* d_ws, size_t ws_size,
                              hipStream_t stream) {
  const float* x      = (const float*)d_in[0];
  const int*   wp     = (const int*)d_in[1];
  const float* cent   = (const float*)d_in[2];
  const float* scales = (const float*)d_in[3];
  float*       out    = (float*)d_out;

  const int K = 4096;
  const int M = in_sizes[0] / K;                        // 8192
  const int O = (int)(((size_t)in_sizes[1] * 2) / K);   // 4096

  size_t need = (size_t)M * K * 2 + (size_t)O * K * 2;  // 96 MiB
  const bool shapes_ok = (M % 256 == 0) && (O % 256 == 0) && (K % 128 == 0);
  if (ws_size >= need && shapes_ok) {
    unsigned short* xb = (unsigned short*)d_ws;
    unsigned short* wb = xb + (size_t)M * K;

    int xthreads = M * K / 16;                 // 16 floats per thread
    int xblocks  = xthreads / 256;             // 2048
    int wthreads = O * K / 16;                 // 16 weights per thread
    int wblocks  = wthreads / 256;             // 1024
    prep_kernel<<<xblocks + wblocks, 256, 0, stream>>>(
        (const float4*)x, (uint4*)xb, xblocks, wp, cent, scales, wb, K);

    dim3 grid((M >> 8) * (O >> 8));            // 32 * 16 = 512 blocks
    gemm_bt8<<<grid, 512, 0, stream>>>(xb, wb, out, M, O, K);
  } else {
    dim3 grid((O + 255) / 256, M);
    naive_kernel<<<grid, 256, 0, stream>>>(x, wp, cent, scales, out, M, O, K);
  }
}

// Round 3
// 1079.509 us; speedup vs baseline: 1.1502x; 1.1502x over previous
//
#include <hip/hip_runtime.h>
#include <stdint.h>

// ---------------------------------------------------------------------------
// QuantizedLinear: out[M,N] = x[M,K] @ dequant(Wpacked)[N,K]^T
//   M = 8192, K = 4096, N = 4096
// R8: R7's read-ahead-by-one-phase schedule, with fragments as NAMED SCALARS
// (R7 passed arrays by pointer into lambdas -> SROA failed -> all frags in
// scratch -> 690 MB of spill HBM traffic, MfmaUtil 11%). No array addresses
// are ever taken here; LDS reads are value-returning lambdas; macros paste
// register names textually.
//
// Schedule per tile T (buf = T&1), quadrants (qm,qn) in order 00,10,11,01:
//   ph1: RD A1(T)->Y;    ST A1(T+1)->buf^1; MFMA(X=A0(T), bA=B0(T)) -> c00,c10
//   ph2: RD B1(T)->bB;   ST B1(T+1)->buf^1; MFMA(Y=A1(T), bA)       -> c20,c30
//   ph3: RD B0(T+1)->bA; ST B0(T+2)->buf;   MFMA(Y, bB=B1(T))       -> c21,c31
//   ph4: RD A0(T+1)->Y;  ST A0(T+2)->buf;   MFMA(X, bB)             -> c01,c11
// X/Y names swap per tile (unroll-2, static). One s_barrier per phase.
// vmcnt(6) at each phase end: steady-state proof — outstanding halves at
// phase start are the last 3 staged; each phase issues 1 half (2 loads) and
// the drain-to-6 retires EXACTLY the half the next phase's RD consumes.
// MFMA consumes registers read LAST phase; compiler inserts counted lgkmcnt
// (waits the 8 prior reads, not this phase's 8). Tail: last 2 tiles peeled
// with vmcnt(0) per phase (stages cease -> counted drain no longer advances).
// Stage-after-read safety: every ST overwrites an LDS region whose last
// ds_read was 4 phases (>=1 barrier) earlier.
// ---------------------------------------------------------------------------

typedef short short8   __attribute__((ext_vector_type(8)));    // 8 bf16
typedef float floatx16 __attribute__((ext_vector_type(16)));   // 32x32 acc

#define BK 64

// round-to-nearest-even fp32 -> bf16 (returned in low 16 bits)
__device__ __forceinline__ uint32_t f2bf(float f) {
  union { float f; uint32_t u; } v; v.f = f;
  return (v.u + 0x7FFFu + ((v.u >> 16) & 1u)) >> 16;
}

// async global->LDS, 16B per lane; LDS dest is wave-uniform base + lane*16
__device__ __forceinline__ void async_copy16(const void* g, void* l) {
  __builtin_amdgcn_global_load_lds(
      (const __attribute__((address_space(1))) uint32_t*)g,
      (__attribute__((address_space(3))) uint32_t*)l, 16, 0, 0);
}

// ----------------- fused prepass: x -> bf16  and  W -> bf16 ----------------
__global__ void prep_kernel(const float4* __restrict__ x, uint4* __restrict__ xb,
                            int xblocks,
                            const int* __restrict__ wp, const float* __restrict__ cent,
                            const float* __restrict__ scales,
                            unsigned short* __restrict__ wb, int K) {
  if ((int)blockIdx.x < xblocks) {
    int t = blockIdx.x * blockDim.x + threadIdx.x;
    float4 v0 = x[4 * t + 0];
    float4 v1 = x[4 * t + 1];
    float4 v2 = x[4 * t + 2];
    float4 v3 = x[4 * t + 3];
    uint4 o0, o1;
    o0.x = f2bf(v0.x) | (f2bf(v0.y) << 16);
    o0.y = f2bf(v0.z) | (f2bf(v0.w) << 16);
    o0.z = f2bf(v1.x) | (f2bf(v1.y) << 16);
    o0.w = f2bf(v1.z) | (f2bf(v1.w) << 16);
    o1.x = f2bf(v2.x) | (f2bf(v2.y) << 16);
    o1.y = f2bf(v2.z) | (f2bf(v2.w) << 16);
    o1.z = f2bf(v3.x) | (f2bf(v3.y) << 16);
    o1.w = f2bf(v3.z) | (f2bf(v3.w) << 16);
    xb[2 * t]     = o0;
    xb[2 * t + 1] = o1;
  } else {
    __shared__ float lut[16];
    if (threadIdx.x < 16) lut[threadIdx.x] = cent[threadIdx.x];
    __syncthreads();
    int u = (blockIdx.x - xblocks) * blockDim.x + threadIdx.x;
    const int tpr = K >> 4;            // threads per row = 256 (pow2)
    int o = u / tpr;
    int j = u & (tpr - 1);
    const int* base = wp + (size_t)o * (K >> 1) + j * 8;
    const int4 p0 = *(const int4*)(base);
    const int4 p1 = *(const int4*)(base + 4);
    int kbase = j * 16;                // 16 weights, single 64-block
    float s = scales[(size_t)o * (K >> 6) + (kbase >> 6)];
    int pb[8] = {p0.x, p0.y, p0.z, p0.w, p1.x, p1.y, p1.z, p1.w};
    uint32_t w32[8];
#pragma unroll
    for (int i = 0; i < 8; ++i) {
      unsigned b = (unsigned)pb[i] & 0xFFu;
      uint32_t hi = f2bf(lut[b >> 4] * s);   // first element of the byte
      uint32_t lo = f2bf(lut[b & 15] * s);   // second element
      w32[i] = hi | (lo << 16);
    }
    uint4* dst = (uint4*)(wb + (size_t)o * K + kbase);
    dst[0] = make_uint4(w32[0], w32[1], w32[2], w32[3]);
    dst[1] = make_uint4(w32[4], w32[5], w32[6], w32[7]);
  }
}

// ------------------------------ main GEMM ----------------------------------
// A[M,K] bf16, B[N,K] bf16 (B^T layout), C[M,N] fp32.
// LDS per buffer: A[256][64] then B[256][64] (shorts). 16B-slot (row,p)
// holds global k-block p ^ (row&7) (involution; write side pre-swizzles the
// global source, read side XORs the same term). Conflict-free: every 8
// consecutive lanes of any ds_read_b128 hit 8 distinct 16B blocks.
__global__ __launch_bounds__(512, 2) void gemm_bt8(const unsigned short* __restrict__ A,
                                                   const unsigned short* __restrict__ B,
                                                   float* __restrict__ C,
                                                   int M, int N, int K) {
  __shared__ unsigned short lds[65536];  // 128 KiB
  const int tid  = threadIdx.x;
  const int lane = tid & 63;
  const int w    = tid >> 6;     // wave 0..7
  const int wm   = w >> 2;       // 2 waves in M (128 rows each)
  const int wn   = w & 3;        // 4 waves in N (64 cols each)

  // bijective XCD-aware block swizzle (nwg = 512, %8 == 0)
  const int nbx = N >> 8;
  const int nwg = gridDim.x;
  const int wg  = blockIdx.x;
  const int swz = ((nwg & 7) == 0) ? ((wg & 7) * (nwg >> 3) + (wg >> 3)) : wg;
  const int bm  = (swz / nbx) << 8;
  const int bn  = (swz % nbx) << 8;

  // ---- staging: pre-swizzled global source, linear LDS dest --------------
  const int srow = lane >> 3;                 // row within an 8-row chunk
  const int sblk = (lane & 7) ^ srow;         // pre-swizzled global 16B-block
  const size_t goff = (size_t)srow * K + sblk * 8;   // shorts
  const unsigned short* Ag = A + (size_t)bm * K + goff;
  const unsigned short* Bg = B + (size_t)bn * K + goff;

  const int nt = K / BK;   // 64

  // A half qm: rows {qm*64+[0,64)} u {128+qm*64+[0,64)}; 2 issues/wave.
  auto stageA = [&](int buf, int kt, int qm) {
#pragma unroll
    for (int i = 0; i < 2; ++i) {
      const int r0 = i * 128 + qm * 64 + w * 8;          // wave-uniform
      async_copy16(Ag + (size_t)r0 * K + kt,
                   (char*)lds + buf * 65536 + r0 * 128);
    }
  };
  // B half qn: rows {qn*32 + j*64 + [0,32) : j=0..3}
  auto stageB = [&](int buf, int kt, int qn) {
#pragma unroll
    for (int i = 0; i < 2; ++i) {
      const int j  = i * 2 + (w >> 2);
      const int r0 = qn * 32 + j * 64 + (w & 3) * 8;     // wave-uniform
      async_copy16(Bg + (size_t)r0 * K + kt,
                   (char*)lds + buf * 65536 + 32768 + r0 * 128);
    }
  };

  // ---- fragment reads (32x32x16: lane holds row lane&31, k (lane>>5)*8+j)
  const int lr = lane & 31;
  const int hi = lane >> 5;
  const int e  = lr & 7;          // row&7 swizzle term (row = 32*m + lr)

  // value-returning LDS reads (no pointers to register arrays anywhere)
  auto LDA = [&](int buf, int qm, int mtl, int s) -> short8 {
    return *(const short8*)(lds + buf * 32768 +
                            ((wm * 128 + (qm * 2 + mtl) * 32 + lr) << 6) +
                            (((2 * s + hi) ^ e) << 3));
  };
  auto LDB = [&](int buf, int qn, int s) -> short8 {
    return *(const short8*)(lds + buf * 32768 + 16384 +
                            ((wn * 64 + qn * 32 + lr) << 6) +
                            (((2 * s + hi) ^ e) << 3));
  };

#define MF(a, b, c) __builtin_amdgcn_mfma_f32_32x32x16_bf16((a), (b), (c), 0, 0, 0)

// read one A half (8 frags: P0-3 = m-subtile 0 k-steps 0-3, P4-7 = m-subtile 1)
#define RD_A(P, buf, qm)                                                    \
  P##0 = LDA((buf), (qm), 0, 0); P##1 = LDA((buf), (qm), 0, 1);             \
  P##2 = LDA((buf), (qm), 0, 2); P##3 = LDA((buf), (qm), 0, 3);             \
  P##4 = LDA((buf), (qm), 1, 0); P##5 = LDA((buf), (qm), 1, 1);             \
  P##6 = LDA((buf), (qm), 1, 2); P##7 = LDA((buf), (qm), 1, 3);

// read one B half (4 frags: k-steps 0-3)
#define RD_B(Q, buf, qn)                                                    \
  Q##0 = LDB((buf), (qn), 0); Q##1 = LDB((buf), (qn), 1);                   \
  Q##2 = LDB((buf), (qn), 2); Q##3 = LDB((buf), (qn), 3);

// 8 MFMA: CA accumulates m-subtile 0, CB m-subtile 1, k-steps 0..3
#define MM8(P, Q, CA, CB)                                                   \
  CA = MF(P##0, Q##0, CA); CB = MF(P##4, Q##0, CB);                         \
  CA = MF(P##1, Q##1, CA); CB = MF(P##5, Q##1, CB);                         \
  CA = MF(P##2, Q##2, CA); CB = MF(P##6, Q##2, CB);                         \
  CA = MF(P##3, Q##3, CA); CB = MF(P##7, Q##3, CB);

#define PH(RD, ST, MM, VM)                                                  \
  __builtin_amdgcn_s_barrier();                                             \
  __builtin_amdgcn_sched_barrier(0);                                        \
  RD;                                                                       \
  ST;                                                                       \
  __builtin_amdgcn_sched_barrier(0);                                        \
  __builtin_amdgcn_s_setprio(1);                                            \
  MM;                                                                       \
  __builtin_amdgcn_s_setprio(0);                                            \
  __builtin_amdgcn_sched_barrier(0);                                        \
  asm volatile("s_waitcnt vmcnt(" #VM ")" ::: "memory");

#define TILE(T, PX, PY, BUF)                                                \
  PH(RD_A(PY, (BUF), 1),     stageA((BUF) ^ 1, ((T) + 1) * BK, 1),          \
     MM8(PX, bA, c00, c10), 6)                                              \
  PH(RD_B(bB, (BUF), 1),     stageB((BUF) ^ 1, ((T) + 1) * BK, 1),          \
     MM8(PY, bA, c20, c30), 6)                                              \
  PH(RD_B(bA, (BUF) ^ 1, 0), stageB((BUF), ((T) + 2) * BK, 0),              \
     MM8(PY, bB, c21, c31), 6)                                              \
  PH(RD_A(PY, (BUF) ^ 1, 0), stageA((BUF), ((T) + 2) * BK, 0),              \
     MM8(PX, bB, c01, c11), 6)

  // named accumulators (c{mt}{nt}): mt = qm*2 + m-subtile, nt = qn
  floatx16 c00 = {}, c01 = {}, c10 = {}, c11 = {};
  floatx16 c20 = {}, c21 = {}, c30 = {}, c31 = {};
  // named fragment registers
  short8 aP0, aP1, aP2, aP3, aP4, aP5, aP6, aP7;
  short8 aQ0, aQ1, aQ2, aQ3, aQ4, aQ5, aQ6, aQ7;
  short8 bA0, bA1, bA2, bA3, bB0, bB1, bB2, bB3;

  // ---- prologue: stage 6 halves oldest-first (= steady drain order) ------
  stageB(0, 0, 0);        // B0(0)
  stageA(0, 0, 0);        // A0(0)
  stageA(0, 0, 1);        // A1(0)
  stageB(0, 0, 1);        // B1(0)
  stageB(1, BK, 0);       // B0(1)
  stageA(1, BK, 0);       // A0(1)
  asm volatile("s_waitcnt vmcnt(6)" ::: "memory");  // drains B0(0),A0(0),A1(0)
  __builtin_amdgcn_s_barrier();
  __builtin_amdgcn_sched_barrier(0);
  RD_A(aP, 0, 0);         // X of tile 0 = A0(0)
  RD_B(bA, 0, 0);         // B0(0)

  // ---- main loop: tiles 0 .. nt-3 (all stages unconditional) -------------
  for (int T = 0; T + 3 < nt; T += 2) {
    TILE(T,     aP, aQ, 0)
    TILE(T + 1, aQ, aP, 1)
  }

  // ---- tail: tiles nt-2 (buf 0) and nt-1 (buf 1), vmcnt(0) per phase -----
  {
    const int Tz = nt - 2;
    PH(RD_A(aQ, 0, 1), stageA(1, (Tz + 1) * BK, 1), MM8(aP, bA, c00, c10), 0)
    PH(RD_B(bB, 0, 1), stageB(1, (Tz + 1) * BK, 1), MM8(aQ, bA, c20, c30), 0)
    PH(RD_B(bA, 1, 0), (void)0,                     MM8(aQ, bB, c21, c31), 0)
    PH(RD_A(aQ, 1, 0), (void)0,                     MM8(aP, bB, c01, c11), 0)
    // tile nt-1: X = aQ, Y = aP
    PH(RD_A(aP, 1, 1), (void)0,                     MM8(aQ, bA, c00, c10), 0)
    PH(RD_B(bB, 1, 1), (void)0,                     MM8(aP, bA, c20, c30), 0)
    PH((void)0,        (void)0,                     MM8(aP, bB, c21, c31), 0)
    PH((void)0,        (void)0,                     MM8(aQ, bB, c01, c11), 0)
  }

#undef TILE
#undef PH
#undef MM8
#undef RD_B
#undef RD_A
#undef MF

  // ---- C store: 32x32 C/D layout (m74/m101):
  // col = lane&31, row = (reg&3) + 8*(reg>>2) + 4*(lane>>5)
#define STORE_ACC(CC, mt, ntl)                                              \
  {                                                                         \
    const floatx16 v = CC;                                                  \
    const int rb  = bm + wm * 128 + (mt) * 32 + 4 * hi;                     \
    const int col = bn + wn * 64 + (ntl) * 32 + lr;                         \
    _Pragma("unroll")                                                       \
    for (int reg = 0; reg < 16; ++reg) {                                    \
      int row = rb + (reg & 3) + 8 * (reg >> 2);                            \
      __builtin_nontemporal_store(v[reg], &C[(size_t)row * N + col]);       \
    }                                                                       \
  }
  STORE_ACC(c00, 0, 0) STORE_ACC(c01, 0, 1)
  STORE_ACC(c10, 1, 0) STORE_ACC(c11, 1, 1)
  STORE_ACC(c20, 2, 0) STORE_ACC(c21, 2, 1)
  STORE_ACC(c30, 3, 0) STORE_ACC(c31, 3, 1)
#undef STORE_ACC
}

// ------------------------- fallback (ws too small) -------------------------
__global__ void naive_kernel(const float* __restrict__ x, const int* __restrict__ wp,
                             const float* __restrict__ cent, const float* __restrict__ scales,
                             float* __restrict__ out, int M, int N, int K) {
  __shared__ float lut[16];
  if (threadIdx.x < 16) lut[threadIdx.x] = cent[threadIdx.x];
  __syncthreads();
  int n = blockIdx.x * blockDim.x + threadIdx.x;
  int m = blockIdx.y;
  if (n >= N || m >= M) return;
  const float* xr = x + (size_t)m * K;
  const int* wr = wp + (size_t)n * (K / 2);
  float acc = 0.f;
  for (int kb = 0; kb < K / 64; ++kb) {
    float s = scales[(size_t)n * (K / 64) + kb];
    float a = 0.f;
    for (int j = 0; j < 32; ++j) {
      unsigned b = (unsigned)wr[kb * 32 + j] & 0xFFu;
      a += xr[kb * 64 + 2 * j] * lut[b >> 4] + xr[kb * 64 + 2 * j + 1] * lut[b & 15];
    }
    acc += a * s;
  }
  out[(size_t)m * N + n] = acc;
}

// ------------------------------- launcher ----------------------------------
extern "C" void kernel_launch(void* const* d_in, const int* in_sizes, int n_in,
                              void* d_out, int out_size, void* d_ws, size_t ws_size,
                              hipStream_t stream) {
  const float* x      = (const float*)d_in[0];
  const int*   wp     = (const int*)d_in[1];
  const float* cent   = (const float*)d_in[2];
  const float* scales = (const float*)d_in[3];
  float*       out    = (float*)d_out;

  const int K = 4096;
  const int M = in_sizes[0] / K;                        // 8192
  const int O = (int)(((size_t)in_sizes[1] * 2) / K);   // 4096

  size_t need = (size_t)M * K * 2 + (size_t)O * K * 2;  // 96 MiB
  const bool shapes_ok = (M % 256 == 0) && (O % 256 == 0) && (K % 128 == 0);
  if (ws_size >= need && shapes_ok) {
    unsigned short* xb = (unsigned short*)d_ws;
    unsigned short* wb = xb + (size_t)M * K;

    int xthreads = M * K / 16;                 // 16 floats per thread
    int xblocks  = xthreads / 256;             // 2048
    int wthreads = O * K / 16;                 // 16 weights per thread
    int wblocks  = wthreads / 256;             // 1024
    prep_kernel<<<xblocks + wblocks, 256, 0, stream>>>(
        (const float4*)x, (uint4*)xb, xblocks, wp, cent, scales, wb, K);

    dim3 grid((M >> 8) * (O >> 8));            // 32 * 16 = 512 blocks
    gemm_bt8<<<grid, 512, 0, stream>>>(xb, wb, out, M, O, K);
  } else {
    dim3 grid((O + 255) / 256, M);
    naive_kernel<<<grid, 256, 0, stream>>>(x, wp, cent, scales, out, M, O, K);
  }
}

// Round 4
// 852.683 us; speedup vs baseline: 1.4562x; 1.2660x over previous
//
#include <hip/hip_runtime.h>
#include <stdint.h>

// ---------------------------------------------------------------------------
// QuantizedLinear: out[M,N] = x[M,K] @ dequant(Wpacked)[N,K]^T
//   M = 8192, K = 4096, N = 4096
// R9: R7/R8 read-ahead-by-one-phase schedule (refcheck-passed twice), with
// the register-pressure fixes:
//   - NO sched_barrier(0) walls (R8's spill: walls forced 12 RD dests + all
//     operands live at once under the 128-VGPR partition -> ~1.1 GB scratch)
//   - LDS read addresses precomputed into 8 shared VGPRs (kA0-3 / kB0-3);
//     each ds_read = shared base + compile-time const offset
//   - fragments remain individually named scalars (no address ever taken)
//
// Schedule per tile T (buf = T&1), quadrants (qm,qn) in order 00,10,11,01:
//   ph1: RD A1(T)->Y;    ST A1(T+1)->buf^1; MFMA(X=A0(T), bA=B0(T)) -> c00,c10
//   ph2: RD B1(T)->bB;   ST B1(T+1)->buf^1; MFMA(Y=A1(T), bA)       -> c20,c30
//   ph3: RD B0(T+1)->bA; ST B0(T+2)->buf;   MFMA(Y, bB=B1(T))       -> c21,c31
//   ph4: RD A0(T+1)->Y;  ST A0(T+2)->buf;   MFMA(X, bB)             -> c01,c11
// X/Y names swap per tile (unroll-2, static). One s_barrier per phase.
// Per-phase vmcnt(6) retires EXACTLY the half the next phase's RD consumes
// (verified drain ledger: prologue 6 halves, issue 1/drain 1 per phase).
// Ordering safety without sched_barriers: RD/ST cannot hoist above the
// previous phase's vmcnt asm ("memory") nor the barrier; each wave drains
// its own stages BEFORE the barrier, so post-barrier all waves' due halves
// have landed. Stage-after-read: every ST overwrites a region whose last
// ds_read (any wave) was 4 phases (>=3 barriers) earlier.
// MFMA consumes registers read LAST phase -> compiler emits counted lgkmcnt
// (near-free). Tail: last 2 tiles peeled with vmcnt(0) per phase.
// ---------------------------------------------------------------------------

typedef short short8   __attribute__((ext_vector_type(8)));    // 8 bf16
typedef float floatx16 __attribute__((ext_vector_type(16)));   // 32x32 acc

#define BK 64

// round-to-nearest-even fp32 -> bf16 (returned in low 16 bits)
__device__ __forceinline__ uint32_t f2bf(float f) {
  union { float f; uint32_t u; } v; v.f = f;
  return (v.u + 0x7FFFu + ((v.u >> 16) & 1u)) >> 16;
}

// async global->LDS, 16B per lane; LDS dest is wave-uniform base + lane*16
__device__ __forceinline__ void async_copy16(const void* g, void* l) {
  __builtin_amdgcn_global_load_lds(
      (const __attribute__((address_space(1))) uint32_t*)g,
      (__attribute__((address_space(3))) uint32_t*)l, 16, 0, 0);
}

// ----------------- fused prepass: x -> bf16  and  W -> bf16 ----------------
__global__ void prep_kernel(const float4* __restrict__ x, uint4* __restrict__ xb,
                            int xblocks,
                            const int* __restrict__ wp, const float* __restrict__ cent,
                            const float* __restrict__ scales,
                            unsigned short* __restrict__ wb, int K) {
  if ((int)blockIdx.x < xblocks) {
    int t = blockIdx.x * blockDim.x + threadIdx.x;
    float4 v0 = x[4 * t + 0];
    float4 v1 = x[4 * t + 1];
    float4 v2 = x[4 * t + 2];
    float4 v3 = x[4 * t + 3];
    uint4 o0, o1;
    o0.x = f2bf(v0.x) | (f2bf(v0.y) << 16);
    o0.y = f2bf(v0.z) | (f2bf(v0.w) << 16);
    o0.z = f2bf(v1.x) | (f2bf(v1.y) << 16);
    o0.w = f2bf(v1.z) | (f2bf(v1.w) << 16);
    o1.x = f2bf(v2.x) | (f2bf(v2.y) << 16);
    o1.y = f2bf(v2.z) | (f2bf(v2.w) << 16);
    o1.z = f2bf(v3.x) | (f2bf(v3.y) << 16);
    o1.w = f2bf(v3.z) | (f2bf(v3.w) << 16);
    xb[2 * t]     = o0;
    xb[2 * t + 1] = o1;
  } else {
    __shared__ float lut[16];
    if (threadIdx.x < 16) lut[threadIdx.x] = cent[threadIdx.x];
    __syncthreads();
    int u = (blockIdx.x - xblocks) * blockDim.x + threadIdx.x;
    const int tpr = K >> 4;            // threads per row = 256 (pow2)
    int o = u / tpr;
    int j = u & (tpr - 1);
    const int* base = wp + (size_t)o * (K >> 1) + j * 8;
    const int4 p0 = *(const int4*)(base);
    const int4 p1 = *(const int4*)(base + 4);
    int kbase = j * 16;                // 16 weights, single 64-block
    float s = scales[(size_t)o * (K >> 6) + (kbase >> 6)];
    int pb[8] = {p0.x, p0.y, p0.z, p0.w, p1.x, p1.y, p1.z, p1.w};
    uint32_t w32[8];
#pragma unroll
    for (int i = 0; i < 8; ++i) {
      unsigned b = (unsigned)pb[i] & 0xFFu;
      uint32_t hi = f2bf(lut[b >> 4] * s);   // first element of the byte
      uint32_t lo = f2bf(lut[b & 15] * s);   // second element
      w32[i] = hi | (lo << 16);
    }
    uint4* dst = (uint4*)(wb + (size_t)o * K + kbase);
    dst[0] = make_uint4(w32[0], w32[1], w32[2], w32[3]);
    dst[1] = make_uint4(w32[4], w32[5], w32[6], w32[7]);
  }
}

// ------------------------------ main GEMM ----------------------------------
// A[M,K] bf16, B[N,K] bf16 (B^T layout), C[M,N] fp32.
// LDS per buffer: A[256][64] then B[256][64] (shorts). 16B-slot (row,p)
// holds global k-block p ^ (row&7) (involution; write side pre-swizzles the
// global source, read side XORs the same term). Conflict-free: every 8
// consecutive lanes of any ds_read_b128 hit 8 distinct 16B blocks.
__global__ __launch_bounds__(512, 2) void gemm_bt8(const unsigned short* __restrict__ A,
                                                   const unsigned short* __restrict__ B,
                                                   float* __restrict__ C,
                                                   int M, int N, int K) {
  __shared__ unsigned short lds[65536];  // 128 KiB
  const char* ldsc = (const char*)lds;
  const int tid  = threadIdx.x;
  const int lane = tid & 63;
  const int w    = tid >> 6;     // wave 0..7
  const int wm   = w >> 2;       // 2 waves in M (128 rows each)
  const int wn   = w & 3;        // 4 waves in N (64 cols each)

  // bijective XCD-aware block swizzle (nwg = 512, %8 == 0)
  const int nbx = N >> 8;
  const int nwg = gridDim.x;
  const int wg  = blockIdx.x;
  const int swz = ((nwg & 7) == 0) ? ((wg & 7) * (nwg >> 3) + (wg >> 3)) : wg;
  const int bm  = (swz / nbx) << 8;
  const int bn  = (swz % nbx) << 8;

  // ---- staging: pre-swizzled global source, linear LDS dest --------------
  const int srow = lane >> 3;                 // row within an 8-row chunk
  const int sblk = (lane & 7) ^ srow;         // pre-swizzled global 16B-block
  const size_t goff = (size_t)srow * K + sblk * 8;   // shorts
  const unsigned short* Ag = A + (size_t)bm * K + goff;
  const unsigned short* Bg = B + (size_t)bn * K + goff;

  const int nt = K / BK;   // 64

  // A half qm: rows {qm*64+[0,64)} u {128+qm*64+[0,64)}; 2 issues/wave.
  auto stageA = [&](int buf, int kt, int qm) {
#pragma unroll
    for (int i = 0; i < 2; ++i) {
      const int r0 = i * 128 + qm * 64 + w * 8;          // wave-uniform
      async_copy16(Ag + (size_t)r0 * K + kt,
                   (char*)lds + buf * 65536 + r0 * 128);
    }
  };
  // B half qn: rows {qn*32 + j*64 + [0,32) : j=0..3}
  auto stageB = [&](int buf, int kt, int qn) {
#pragma unroll
    for (int i = 0; i < 2; ++i) {
      const int j  = i * 2 + (w >> 2);
      const int r0 = qn * 32 + j * 64 + (w & 3) * 8;     // wave-uniform
      async_copy16(Bg + (size_t)r0 * K + kt,
                   (char*)lds + buf * 65536 + 32768 + r0 * 128);
    }
  };

  // ---- fragment read addressing (32x32x16: row = lane&31, kgrp = lane>>5)
  const int lr = lane & 31;
  const int hi = lane >> 5;
  const int e  = lr & 7;          // row&7 swizzle term (row = 32*m + lr)

  // shared dynamic byte addresses (8 VGPRs); all else is const offsets
  const int adA = (wm * 128 + lr) * 128;           // A row base (buf0, qm0,mtl0)
  const int adB = 32768 + (wn * 64 + lr) * 128;    // B row base (buf0, qn0)
  const int kA0 = adA + (((0 + hi) ^ e) << 4);
  const int kA1 = adA + (((2 + hi) ^ e) << 4);
  const int kA2 = adA + (((4 + hi) ^ e) << 4);
  const int kA3 = adA + (((6 + hi) ^ e) << 4);
  const int kB0 = adB + (((0 + hi) ^ e) << 4);
  const int kB1 = adB + (((2 + hi) ^ e) << 4);
  const int kB2 = adB + (((4 + hi) ^ e) << 4);
  const int kB3 = adB + (((6 + hi) ^ e) << 4);

  auto LD = [&](int dyn, int cst) -> short8 {
    return *(const short8*)(ldsc + dyn + cst);
  };

#define MF(a, b, c) __builtin_amdgcn_mfma_f32_32x32x16_bf16((a), (b), (c), 0, 0, 0)

// read one A half (8 frags: P0-3 = m-subtile 0 k-steps 0-3, P4-7 = m-subtile 1)
// byte offset: buf*65536 + (qm*2+mtl)*4096
#define RD_A(P, BUF, qm)                                                    \
  P##0 = LD(kA0, (BUF) * 65536 + (qm) * 8192);                              \
  P##1 = LD(kA1, (BUF) * 65536 + (qm) * 8192);                              \
  P##2 = LD(kA2, (BUF) * 65536 + (qm) * 8192);                              \
  P##3 = LD(kA3, (BUF) * 65536 + (qm) * 8192);                              \
  P##4 = LD(kA0, (BUF) * 65536 + (qm) * 8192 + 4096);                       \
  P##5 = LD(kA1, (BUF) * 65536 + (qm) * 8192 + 4096);                       \
  P##6 = LD(kA2, (BUF) * 65536 + (qm) * 8192 + 4096);                       \
  P##7 = LD(kA3, (BUF) * 65536 + (qm) * 8192 + 4096);

// read one B half (4 frags: k-steps 0-3); byte offset: buf*65536 + qn*4096
#define RD_B(Q, BUF, qn)                                                    \
  Q##0 = LD(kB0, (BUF) * 65536 + (qn) * 4096);                              \
  Q##1 = LD(kB1, (BUF) * 65536 + (qn) * 4096);                              \
  Q##2 = LD(kB2, (BUF) * 65536 + (qn) * 4096);                              \
  Q##3 = LD(kB3, (BUF) * 65536 + (qn) * 4096);

// 8 MFMA: CA accumulates m-subtile 0, CB m-subtile 1, k-steps 0..3
#define MM8(P, Q, CA, CB)                                                   \
  CA = MF(P##0, Q##0, CA); CB = MF(P##4, Q##0, CB);                         \
  CA = MF(P##1, Q##1, CA); CB = MF(P##5, Q##1, CB);                         \
  CA = MF(P##2, Q##2, CA); CB = MF(P##6, Q##2, CB);                         \
  CA = MF(P##3, Q##3, CA); CB = MF(P##7, Q##3, CB);

#define PH(RD, ST, MM, VM)                                                  \
  __builtin_amdgcn_s_barrier();                                             \
  RD;                                                                       \
  ST;                                                                       \
  __builtin_amdgcn_s_setprio(1);                                            \
  MM;                                                                       \
  __builtin_amdgcn_s_setprio(0);                                            \
  asm volatile("s_waitcnt vmcnt(" #VM ")" ::: "memory");

#define TILE(T, PX, PY, BUF)                                                \
  PH(RD_A(PY, (BUF), 1),     stageA((BUF) ^ 1, ((T) + 1) * BK, 1),          \
     MM8(PX, bA, c00, c10), 6)                                              \
  PH(RD_B(bB, (BUF), 1),     stageB((BUF) ^ 1, ((T) + 1) * BK, 1),          \
     MM8(PY, bA, c20, c30), 6)                                              \
  PH(RD_B(bA, (BUF) ^ 1, 0), stageB((BUF), ((T) + 2) * BK, 0),              \
     MM8(PY, bB, c21, c31), 6)                                              \
  PH(RD_A(PY, (BUF) ^ 1, 0), stageA((BUF), ((T) + 2) * BK, 0),              \
     MM8(PX, bB, c01, c11), 6)

  // named accumulators (c{mt}{nt}): mt = qm*2 + m-subtile, nt = qn
  floatx16 c00 = {}, c01 = {}, c10 = {}, c11 = {};
  floatx16 c20 = {}, c21 = {}, c30 = {}, c31 = {};
  // named fragment registers
  short8 aP0, aP1, aP2, aP3, aP4, aP5, aP6, aP7;
  short8 aQ0, aQ1, aQ2, aQ3, aQ4, aQ5, aQ6, aQ7;
  short8 bA0, bA1, bA2, bA3, bB0, bB1, bB2, bB3;

  // ---- prologue: stage 6 halves oldest-first (= steady drain order) ------
  stageB(0, 0, 0);        // B0(0)
  stageA(0, 0, 0);        // A0(0)
  stageA(0, 0, 1);        // A1(0)
  stageB(0, 0, 1);        // B1(0)
  stageB(1, BK, 0);       // B0(1)
  stageA(1, BK, 0);       // A0(1)
  asm volatile("s_waitcnt vmcnt(6)" ::: "memory");  // drains B0(0),A0(0),A1(0)
  __builtin_amdgcn_s_barrier();
  RD_A(aP, 0, 0);         // X of tile 0 = A0(0)
  RD_B(bA, 0, 0);         // B0(0)

  // ---- main loop: tiles 0 .. nt-3 (all stages unconditional) -------------
  for (int T = 0; T + 3 < nt; T += 2) {
    TILE(T,     aP, aQ, 0)
    TILE(T + 1, aQ, aP, 1)
  }

  // ---- tail: tiles nt-2 (buf 0) and nt-1 (buf 1), vmcnt(0) per phase -----
  {
    const int Tz = nt - 2;
    PH(RD_A(aQ, 0, 1), stageA(1, (Tz + 1) * BK, 1), MM8(aP, bA, c00, c10), 0)
    PH(RD_B(bB, 0, 1), stageB(1, (Tz + 1) * BK, 1), MM8(aQ, bA, c20, c30), 0)
    PH(RD_B(bA, 1, 0), (void)0,                     MM8(aQ, bB, c21, c31), 0)
    PH(RD_A(aQ, 1, 0), (void)0,                     MM8(aP, bB, c01, c11), 0)
    // tile nt-1: X = aQ, Y = aP
    PH(RD_A(aP, 1, 1), (void)0,                     MM8(aQ, bA, c00, c10), 0)
    PH(RD_B(bB, 1, 1), (void)0,                     MM8(aP, bA, c20, c30), 0)
    PH((void)0,        (void)0,                     MM8(aP, bB, c21, c31), 0)
    PH((void)0,        (void)0,                     MM8(aQ, bB, c01, c11), 0)
  }

#undef TILE
#undef PH
#undef MM8
#undef RD_B
#undef RD_A
#undef MF

  // ---- C store: 32x32 C/D layout (m74/m101):
  // col = lane&31, row = (reg&3) + 8*(reg>>2) + 4*(lane>>5)
#define STORE_ACC(CC, mt, ntl)                                              \
  {                                                                         \
    const floatx16 v = CC;                                                  \
    const int rb  = bm + wm * 128 + (mt) * 32 + 4 * hi;                     \
    const int col = bn + wn * 64 + (ntl) * 32 + lr;                         \
    _Pragma("unroll")                                                       \
    for (int reg = 0; reg < 16; ++reg) {                                    \
      int row = rb + (reg & 3) + 8 * (reg >> 2);                            \
      __builtin_nontemporal_store(v[reg], &C[(size_t)row * N + col]);       \
    }                                                                       \
  }
  STORE_ACC(c00, 0, 0) STORE_ACC(c01, 0, 1)
  STORE_ACC(c10, 1, 0) STORE_ACC(c11, 1, 1)
  STORE_ACC(c20, 2, 0) STORE_ACC(c21, 2, 1)
  STORE_ACC(c30, 3, 0) STORE_ACC(c31, 3, 1)
#undef STORE_ACC
}

// ------------------------- fallback (ws too small) -------------------------
__global__ void naive_kernel(const float* __restrict__ x, const int* __restrict__ wp,
                             const float* __restrict__ cent, const float* __restrict__ scales,
                             float* __restrict__ out, int M, int N, int K) {
  __shared__ float lut[16];
  if (threadIdx.x < 16) lut[threadIdx.x] = cent[threadIdx.x];
  __syncthreads();
  int n = blockIdx.x * blockDim.x + threadIdx.x;
  int m = blockIdx.y;
  if (n >= N || m >= M) return;
  const float* xr = x + (size_t)m * K;
  const int* wr = wp + (size_t)n * (K / 2);
  float acc = 0.f;
  for (int kb = 0; kb < K / 64; ++kb) {
    float s = scales[(size_t)n * (K / 64) + kb];
    float a = 0.f;
    for (int j = 0; j < 32; ++j) {
      unsigned b = (unsigned)wr[kb * 32 + j] & 0xFFu;
      a += xr[kb * 64 + 2 * j] * lut[b >> 4] + xr[kb * 64 + 2 * j + 1] * lut[b & 15];
    }
    acc += a * s;
  }
  out[(size_t)m * N + n] = acc;
}

// ------------------------------- launcher ----------------------------------
extern "C" void kernel_launch(void* const* d_in, const int* in_sizes, int n_in,
                              void* d_out, int out_size, void* d_ws, size_t ws_size,
                              hipStream_t stream) {
  const float* x      = (const float*)d_in[0];
  const int*   wp     = (const int*)d_in[1];
  const float* cent   = (const float*)d_in[2];
  const float* scales = (const float*)d_in[3];
  float*       out    = (float*)d_out;

  const int K = 4096;
  const int M = in_sizes[0] / K;                        // 8192
  const int O = (int)(((size_t)in_sizes[1] * 2) / K);   // 4096

  size_t need = (size_t)M * K * 2 + (size_t)O * K * 2;  // 96 MiB
  const bool shapes_ok = (M % 256 == 0) && (O % 256 == 0) && (K % 128 == 0);
  if (ws_size >= need && shapes_ok) {
    unsigned short* xb = (unsigned short*)d_ws;
    unsigned short* wb = xb + (size_t)M * K;

    int xthreads = M * K / 16;                 // 16 floats per thread
    int xblocks  = xthreads / 256;             // 2048
    int wthreads = O * K / 16;                 // 16 weights per thread
    int wblocks  = wthreads / 256;             // 1024
    prep_kernel<<<xblocks + wblocks, 256, 0, stream>>>(
        (const float4*)x, (uint4*)xb, xblocks, wp, cent, scales, wb, K);

    dim3 grid((M >> 8) * (O >> 8));            // 32 * 16 = 512 blocks
    gemm_bt8<<<grid, 512, 0, stream>>>(xb, wb, out, M, O, K);
  } else {
    dim3 grid((O + 255) / 256, M);
    naive_kernel<<<grid, 256, 0, stream>>>(x, wp, cent, scales, out, M, O, K);
  }
}

// Round 5
// 480.182 us; speedup vs baseline: 2.5858x; 1.7757x over previous
//
#include <hip/hip_runtime.h>
#include <stdint.h>

// ---------------------------------------------------------------------------
// QuantizedLinear: out[M,N] = x[M,K] @ dequant(Wpacked)[N,K]^T
//   M = 8192, K = 4096, N = 4096
// R10: GEMM reverted to the verified R6 8-phase kernel (269 us, MfmaUtil 44.5,
// zero spill/conflicts). R7-R9's read-ahead pipeline is register-infeasible:
// 2 waves/SIMD -> 256 unified regs/wave; 128 acc (AGPR) + 96 frag VGPR + ~30
// addressing > cap -> chronic scratch spill (1.1-1.6 GB extra HBM traffic).
// This round's change: PREP coalescing. Old prep gave each lane 4 consecutive
// float4s (per-instr lane stride 64B) and ran at ~1.3 TB/s (211 us for a
// ~43 us roofline). New prep: every load/store is lane-contiguous
// (x: 4-deep strided float4->uint2; W: one int4 -> one uint4 per thread).
// ---------------------------------------------------------------------------

typedef short short8  __attribute__((ext_vector_type(8)));    // 8 bf16 = 4 VGPR
typedef float floatx4 __attribute__((ext_vector_type(4)));    // 16x16 MFMA acc

#define BK 64

// round-to-nearest-even fp32 -> bf16 (returned in low 16 bits)
__device__ __forceinline__ uint32_t f2bf(float f) {
  union { float f; uint32_t u; } v; v.f = f;
  return (v.u + 0x7FFFu + ((v.u >> 16) & 1u)) >> 16;
}

// async global->LDS, 16B per lane; LDS dest is wave-uniform base + lane*16
__device__ __forceinline__ void async_copy16(const void* g, void* l) {
  __builtin_amdgcn_global_load_lds(
      (const __attribute__((address_space(1))) uint32_t*)g,
      (__attribute__((address_space(3))) uint32_t*)l, 16, 0, 0);
}

// ----------------- fused prepass: x -> bf16  and  W -> bf16 ----------------
// x-part: xthreads = M*K/16, each thread converts 4 float4s at stride NT
// (lane-contiguous per instruction). W-part: wthreads = O*K/8, each thread
// one int4 (4 byte-valued ints = 8 weights, single 64-block) -> one uint4.
__global__ void prep_kernel(const float4* __restrict__ x, uint2* __restrict__ xb,
                            int xblocks,
                            const int4* __restrict__ wp4, const float* __restrict__ cent,
                            const float* __restrict__ scales,
                            uint4* __restrict__ wb4, int K) {
  if ((int)blockIdx.x < xblocks) {
    const int NT = xblocks * blockDim.x;             // total x threads
    int t = blockIdx.x * blockDim.x + threadIdx.x;
#pragma unroll
    for (int it = 0; it < 4; ++it) {
      const int i = t + it * NT;                     // float4 index, coalesced
      float4 v = x[i];
      uint2 o;
      o.x = f2bf(v.x) | (f2bf(v.y) << 16);
      o.y = f2bf(v.z) | (f2bf(v.w) << 16);
      xb[i] = o;
    }
  } else {
    __shared__ float lut[16];
    if (threadIdx.x < 16) lut[threadIdx.x] = cent[threadIdx.x];
    __syncthreads();
    const int u = (blockIdx.x - xblocks) * blockDim.x + threadIdx.x;
    const int ipr = K >> 3;              // int4s per row = 512 (pow2)
    const int o = u >> 9;                // row  (u / 512)
    const int j = u & (ipr - 1);         // int4 index in row; weights k0 = j*8
    const float s = scales[(size_t)o * (K >> 6) + (j >> 3)];  // 8 wts, 1 block
    const int4 p = wp4[u];
    uint4 r;
    {
      unsigned b = (unsigned)p.x & 0xFFu;
      r.x = f2bf(lut[b >> 4] * s) | (f2bf(lut[b & 15] * s) << 16);
    }
    {
      unsigned b = (unsigned)p.y & 0xFFu;
      r.y = f2bf(lut[b >> 4] * s) | (f2bf(lut[b & 15] * s) << 16);
    }
    {
      unsigned b = (unsigned)p.z & 0xFFu;
      r.z = f2bf(lut[b >> 4] * s) | (f2bf(lut[b & 15] * s) << 16);
    }
    {
      unsigned b = (unsigned)p.w & 0xFFu;
      r.w = f2bf(lut[b >> 4] * s) | (f2bf(lut[b & 15] * s) << 16);
    }
    wb4[u] = r;                          // 16B store, lane-contiguous
  }
}

// ------------------------------ main GEMM (R6, verified) -------------------
// A[M,K] bf16, B[N,K] bf16 (B^T layout), C[M,N] fp32.
// LDS per buffer: A[256][64] then B[256][64] (shorts). 16B-slot (row, p)
// holds global 16B-block p ^ (row&7) (involution):
//   write side: lane l (srow=l>>3, p=l&7) sources global block (l&7)^srow;
//   read  side: logical block g at row r lives at slot g ^ (r&7).
__global__ __launch_bounds__(512, 2) void gemm_bt8(const unsigned short* __restrict__ A,
                                                   const unsigned short* __restrict__ B,
                                                   float* __restrict__ C,
                                                   int M, int N, int K) {
  __shared__ unsigned short lds[65536];  // 128 KiB: 2 x (A 16K shorts | B 16K shorts)
  const int tid  = threadIdx.x;
  const int lane = tid & 63;
  const int w    = tid >> 6;     // wave 0..7
  const int wm   = w >> 2;       // 2 waves in M
  const int wn   = w & 3;        // 4 waves in N

  // bijective XCD-aware block swizzle (nwg = 512, %8 == 0)
  const int nbx = N >> 8;
  const int nwg = gridDim.x;
  const int wg  = blockIdx.x;
  const int swz = ((nwg & 7) == 0) ? ((wg & 7) * (nwg >> 3) + (wg >> 3)) : wg;
  const int bm  = (swz / nbx) << 8;
  const int bn  = (swz % nbx) << 8;

  // ---- staging: pre-swizzled global source, linear LDS dest --------------
  const int srow = lane >> 3;                 // row within an 8-row chunk
  const int sblk = (lane & 7) ^ srow;         // pre-swizzled global 16B-block
  const size_t goff = (size_t)srow * K + sblk * 8;   // shorts
  const unsigned short* Ag = A + (size_t)bm * K + goff;
  const unsigned short* Bg = B + (size_t)bn * K + goff;

  const int nt = K / BK;

  // A half qm: LDS rows {qm*64+[0,64), 128+qm*64+[0,64)}; 2 issues x 8KiB.
  auto stageA = [&](int buf, int kt, int qm) {
#pragma unroll
    for (int i = 0; i < 2; ++i) {
      const int r0 = i * 128 + qm * 64 + w * 8;          // wave-uniform
      async_copy16(Ag + (size_t)r0 * K + kt,
                   (char*)lds + buf * 65536 + r0 * 128);
    }
  };
  // B half qn: LDS rows {qn*32 + j*64 + [0,32) : j=0..3}
  auto stageB = [&](int buf, int kt, int qn) {
#pragma unroll
    for (int i = 0; i < 2; ++i) {
      const int j  = i * 2 + (w >> 2);
      const int r0 = qn * 32 + j * 64 + (w & 3) * 8;     // wave-uniform
      async_copy16(Bg + (size_t)r0 * K + kt,
                   (char*)lds + buf * 65536 + 32768 + r0 * 128);
    }
  };

  // ---- fragment reads (16x16x32: lane holds row lane&15, k (lane>>4)*8+j)
  const int lrow  = lane & 15;
  const int g16   = lane >> 4;
  const int e8    = lane & 7;
  const int pblk0 = ((0 + g16) ^ e8) << 3;   // shorts; k-step s=0
  const int pblk1 = ((4 + g16) ^ e8) << 3;   // k-step s=1

  auto ldA = [&](int buf, int qm, int f, int s) -> short8 {
    return *(const short8*)(lds + buf * 32768 +
                            ((wm * 128 + qm * 64 + f * 16 + lrow) << 6) +
                            (s ? pblk1 : pblk0));
  };
  auto ldB = [&](int buf, int qn, int f2, int s) -> short8 {
    return *(const short8*)(lds + buf * 32768 + 16384 +
                            ((wn * 64 + qn * 32 + f2 * 16 + lrow) << 6) +
                            (s ? pblk1 : pblk0));
  };

  floatx4 acc[2][2][4][2] = {};   // [qm][qn][m-frag][n-frag]
  short8 a[4][2];                 // current qm half: [m-frag][k-step]
  short8 b0[2][2], b1[2][2];      // qn halves, cached across qm phases

  // ---- prologue: tile0 (4 halves) + tile1 (3 halves); drain tile0 --------
  stageA(0, 0, 0);
  stageB(0, 0, 0);
  stageB(0, 0, 1);
  stageA(0, 0, 1);
  if (nt > 1) {
    stageA(1, BK, 0);
    stageB(1, BK, 0);
    stageB(1, BK, 1);
    asm volatile("s_waitcnt vmcnt(6)" ::: "memory");
  } else {
    asm volatile("s_waitcnt vmcnt(0)" ::: "memory");
  }
  __builtin_amdgcn_s_barrier();

#pragma unroll 2
  for (int T = 0; T < nt; ++T) {
    const int buf = T & 1;
    const int kt2 = (T + 2) * BK;

    // ---------------- phase 1: (qm0, qn0) ----------------
#pragma unroll
    for (int f = 0; f < 4; ++f) { a[f][0] = ldA(buf, 0, f, 0); a[f][1] = ldA(buf, 0, f, 1); }
#pragma unroll
    for (int f2 = 0; f2 < 2; ++f2) { b0[f2][0] = ldB(buf, 0, f2, 0); b0[f2][1] = ldB(buf, 0, f2, 1); }
    if (T + 1 < nt) stageA(buf ^ 1, (T + 1) * BK, 1);
    __builtin_amdgcn_s_barrier();
    asm volatile("s_waitcnt lgkmcnt(0)" ::: "memory");
    __builtin_amdgcn_s_setprio(1);
#pragma unroll
    for (int f = 0; f < 4; ++f)
#pragma unroll
      for (int f2 = 0; f2 < 2; ++f2) {
        acc[0][0][f][f2] = __builtin_amdgcn_mfma_f32_16x16x32_bf16(a[f][0], b0[f2][0], acc[0][0][f][f2], 0, 0, 0);
        acc[0][0][f][f2] = __builtin_amdgcn_mfma_f32_16x16x32_bf16(a[f][1], b0[f2][1], acc[0][0][f][f2], 0, 0, 0);
      }
    __builtin_amdgcn_s_setprio(0);
    __builtin_amdgcn_s_barrier();

    // ---------------- phase 2: (qm0, qn1) ----------------
#pragma unroll
    for (int f2 = 0; f2 < 2; ++f2) { b1[f2][0] = ldB(buf, 1, f2, 0); b1[f2][1] = ldB(buf, 1, f2, 1); }
    if (T + 2 < nt) stageA(buf, kt2, 0);
    __builtin_amdgcn_s_barrier();
    asm volatile("s_waitcnt lgkmcnt(0)" ::: "memory");
    __builtin_amdgcn_s_setprio(1);
#pragma unroll
    for (int f = 0; f < 4; ++f)
#pragma unroll
      for (int f2 = 0; f2 < 2; ++f2) {
        acc[0][1][f][f2] = __builtin_amdgcn_mfma_f32_16x16x32_bf16(a[f][0], b1[f2][0], acc[0][1][f][f2], 0, 0, 0);
        acc[0][1][f][f2] = __builtin_amdgcn_mfma_f32_16x16x32_bf16(a[f][1], b1[f2][1], acc[0][1][f][f2], 0, 0, 0);
      }
    __builtin_amdgcn_s_setprio(0);
    __builtin_amdgcn_s_barrier();

    // ---------------- phase 3: (qm1, qn0) ----------------
#pragma unroll
    for (int f = 0; f < 4; ++f) { a[f][0] = ldA(buf, 1, f, 0); a[f][1] = ldA(buf, 1, f, 1); }
    if (T + 2 < nt) stageB(buf, kt2, 0);
    __builtin_amdgcn_s_barrier();
    asm volatile("s_waitcnt lgkmcnt(0)" ::: "memory");
    __builtin_amdgcn_s_setprio(1);
#pragma unroll
    for (int f = 0; f < 4; ++f)
#pragma unroll
      for (int f2 = 0; f2 < 2; ++f2) {
        acc[1][0][f][f2] = __builtin_amdgcn_mfma_f32_16x16x32_bf16(a[f][0], b0[f2][0], acc[1][0][f][f2], 0, 0, 0);
        acc[1][0][f][f2] = __builtin_amdgcn_mfma_f32_16x16x32_bf16(a[f][1], b0[f2][1], acc[1][0][f][f2], 0, 0, 0);
      }
    __builtin_amdgcn_s_setprio(0);
    __builtin_amdgcn_s_barrier();

    // ---------------- phase 4: (qm1, qn1) ----------------
    if (T + 2 < nt) stageB(buf, kt2, 1);
    __builtin_amdgcn_s_barrier();
    asm volatile("s_waitcnt lgkmcnt(0)" ::: "memory");
    __builtin_amdgcn_s_setprio(1);
#pragma unroll
    for (int f = 0; f < 4; ++f)
#pragma unroll
      for (int f2 = 0; f2 < 2; ++f2) {
        acc[1][1][f][f2] = __builtin_amdgcn_mfma_f32_16x16x32_bf16(a[f][0], b1[f2][0], acc[1][1][f][f2], 0, 0, 0);
        acc[1][1][f][f2] = __builtin_amdgcn_mfma_f32_16x16x32_bf16(a[f][1], b1[f2][1], acc[1][1][f][f2], 0, 0, 0);
      }
    __builtin_amdgcn_s_setprio(0);
    if (T + 2 < nt) {
      asm volatile("s_waitcnt vmcnt(6)" ::: "memory");   // steady: 3 halves in flight
    } else if (T + 1 < nt) {
      asm volatile("s_waitcnt vmcnt(0)" ::: "memory");   // epilogue drain
    }
    __builtin_amdgcn_s_barrier();
  }

  // ---- C store: 16x16 C/D layout (m89): col = lane&15, row = (lane>>4)*4+reg
#pragma unroll
  for (int qm = 0; qm < 2; ++qm)
#pragma unroll
    for (int qn = 0; qn < 2; ++qn)
#pragma unroll
      for (int f = 0; f < 4; ++f)
#pragma unroll
        for (int f2 = 0; f2 < 2; ++f2) {
          const floatx4 v = acc[qm][qn][f][f2];
          const int row0 = bm + wm * 128 + qm * 64 + f * 16 + g16 * 4;
          const int col  = bn + wn * 64 + qn * 32 + f2 * 16 + lrow;
          float* cp = C + (size_t)row0 * N + col;
#pragma unroll
          for (int r = 0; r < 4; ++r)
            __builtin_nontemporal_store(v[r], cp + (size_t)r * N);
        }
}

// ------------------------- fallback (ws too small) -------------------------
__global__ void naive_kernel(const float* __restrict__ x, const int* __restrict__ wp,
                             const float* __restrict__ cent, const float* __restrict__ scales,
                             float* __restrict__ out, int M, int N, int K) {
  __shared__ float lut[16];
  if (threadIdx.x < 16) lut[threadIdx.x] = cent[threadIdx.x];
  __syncthreads();
  int n = blockIdx.x * blockDim.x + threadIdx.x;
  int m = blockIdx.y;
  if (n >= N || m >= M) return;
  const float* xr = x + (size_t)m * K;
  const int* wr = wp + (size_t)n * (K / 2);
  float acc = 0.f;
  for (int kb = 0; kb < K / 64; ++kb) {
    float s = scales[(size_t)n * (K / 64) + kb];
    float a = 0.f;
    for (int j = 0; j < 32; ++j) {
      unsigned b = (unsigned)wr[kb * 32 + j] & 0xFFu;
      a += xr[kb * 64 + 2 * j] * lut[b >> 4] + xr[kb * 64 + 2 * j + 1] * lut[b & 15];
    }
    acc += a * s;
  }
  out[(size_t)m * N + n] = acc;
}

// ------------------------------- launcher ----------------------------------
extern "C" void kernel_launch(void* const* d_in, const int* in_sizes, int n_in,
                              void* d_out, int out_size, void* d_ws, size_t ws_size,
                              hipStream_t stream) {
  const float* x      = (const float*)d_in[0];
  const int*   wp     = (const int*)d_in[1];
  const float* cent   = (const float*)d_in[2];
  const float* scales = (const float*)d_in[3];
  float*       out    = (float*)d_out;

  const int K = 4096;
  const int M = in_sizes[0] / K;                        // 8192
  const int O = (int)(((size_t)in_sizes[1] * 2) / K);   // 4096

  size_t need = (size_t)M * K * 2 + (size_t)O * K * 2;  // 96 MiB
  const bool shapes_ok = (M % 256 == 0) && (O % 256 == 0) && (K % 64 == 0);
  if (ws_size >= need && shapes_ok) {
    unsigned short* xb = (unsigned short*)d_ws;
    unsigned short* wb = xb + (size_t)M * K;

    int xthreads = M * K / 16;                 // 4 float4s per thread
    int xblocks  = xthreads / 256;             // 8192
    int wthreads = O * K / 8;                  // one int4 (8 weights) per thread
    int wblocks  = wthreads / 256;             // 8192
    prep_kernel<<<xblocks + wblocks, 256, 0, stream>>>(
        (const float4*)x, (uint2*)xb, xblocks,
        (const int4*)wp, cent, scales, (uint4*)wb, K);

    dim3 grid((M >> 8) * (O >> 8));            // 32 * 16 = 512 blocks
    gemm_bt8<<<grid, 512, 0, stream>>>(xb, wb, out, M, O, K);
  } else {
    dim3 grid((O + 255) / 256, M);
    naive_kernel<<<grid, 256, 0, stream>>>(x, wp, cent, scales, out, M, O, K);
  }
}